// Round 5
// baseline (7526.543 us; speedup 1.0000x reference)
//
#include <hip/hip_runtime.h>
#include <hip/hip_bf16.h>

// LSTM: T=8192, IN=3000, H=100 (4H=400), torch gate order i,f,g,o.
// Phase 1: xg[T][400] = input_seq @ w_ih^T + (b_ih + b_hh)   (fp32 tiled GEMM)
// Phase 2: single-workgroup scan, 256 threads / 4 waves.
//   Group 0 (tid<128): unit u, gate rows u (i), u+100 (f)
//   Group 1 (tid>=128): unit u, gate rows u+200 (g), u+300 (o)
// ROUND-5 FIX: rounds 1-4 never actually kept w_hh in registers (R4:
// VGPR_Count=108 < 104 weights + working set) — the values are remat-able
// loads, so the allocator re-streamed them from cache every step
// (~106 KB/step through the L1 port ~= the whole 1570 cyc/step).
// Now: (a) every weight value is pinned via empty inline-asm "+v" so it
// cannot be rematerialized; (b) amdgpu_waves_per_eu(1,1) gives the
// allocator the full 512-VGPR budget so it never prefers a spill.

#define GBM 128
#define GBN 128
#define GBK 16

typedef _Float16 h2_t __attribute__((ext_vector_type(2)));

__global__ __launch_bounds__(256) void gates_gemm(
    const float* __restrict__ A,    // [T][IN]
    const float* __restrict__ W,    // [FH][IN]
    const float* __restrict__ bih,  // [FH]
    const float* __restrict__ bhh,  // [FH]
    float* __restrict__ XG,         // [T][FH]
    int T, int IN, int FH)
{
    __shared__ __align__(16) float As[GBK][GBM];
    __shared__ __align__(16) float Bs[GBK][GBN];
    const int bm = blockIdx.x * GBM;
    const int bn = blockIdx.y * GBN;
    const int tid = (int)threadIdx.x;
    const int tx = tid & 15, ty = tid >> 4;

    float acc[8][8];
    #pragma unroll
    for (int i = 0; i < 8; ++i)
        #pragma unroll
        for (int j = 0; j < 8; ++j) acc[i][j] = 0.f;

    for (int k0 = 0; k0 < IN; k0 += GBK) {
        __syncthreads();
        #pragma unroll
        for (int q = 0; q < 2; ++q) {
            int idx = tid + q * 256;
            int row = idx >> 2;
            int kq  = (idx & 3) << 2;
            int gk  = k0 + kq;
            float4 av = make_float4(0.f, 0.f, 0.f, 0.f);
            float4 bv = make_float4(0.f, 0.f, 0.f, 0.f);
            if (gk < IN) {
                av = *(const float4*)&A[(size_t)(bm + row) * IN + gk];
                if (bn + row < FH)
                    bv = *(const float4*)&W[(size_t)(bn + row) * IN + gk];
            }
            As[kq + 0][row] = av.x; As[kq + 1][row] = av.y;
            As[kq + 2][row] = av.z; As[kq + 3][row] = av.w;
            Bs[kq + 0][row] = bv.x; Bs[kq + 1][row] = bv.y;
            Bs[kq + 2][row] = bv.z; Bs[kq + 3][row] = bv.w;
        }
        __syncthreads();
        #pragma unroll
        for (int kk = 0; kk < GBK; ++kk) {
            float4 a0 = *(const float4*)&As[kk][ty * 4];
            float4 a1 = *(const float4*)&As[kk][64 + ty * 4];
            float4 b0 = *(const float4*)&Bs[kk][tx * 4];
            float4 b1 = *(const float4*)&Bs[kk][64 + tx * 4];
            float am[8] = {a0.x, a0.y, a0.z, a0.w, a1.x, a1.y, a1.z, a1.w};
            float bn_[8] = {b0.x, b0.y, b0.z, b0.w, b1.x, b1.y, b1.z, b1.w};
            #pragma unroll
            for (int i = 0; i < 8; ++i)
                #pragma unroll
                for (int j = 0; j < 8; ++j)
                    acc[i][j] = fmaf(am[i], bn_[j], acc[i][j]);
        }
    }

    #pragma unroll
    for (int i = 0; i < 8; ++i) {
        int r = bm + ((i < 4) ? (ty * 4 + i) : (64 + ty * 4 + (i - 4)));
        #pragma unroll
        for (int j = 0; j < 8; ++j) {
            int cidx = bn + ((j < 4) ? (tx * 4 + j) : (64 + tx * 4 + (j - 4)));
            if (cidx < FH)
                XG[(size_t)r * FH + cidx] = acc[i][j] + bih[cidx] + bhh[cidx];
        }
    }
}

__device__ __forceinline__ float sigmoid_fast(float x) {
    return 1.f / (1.f + __expf(-x));
}
__device__ __forceinline__ float tanh_fast(float x) {
    // tanh(x) = 1 - 2/(exp(2x)+1); exp saturation gives correct +-1 limits.
    return 1.f - 2.f / (__expf(2.f * x) + 1.f);
}

__global__ __launch_bounds__(256, 1)
__attribute__((amdgpu_waves_per_eu(1, 1)))
void lstm_scan4(
    const float* __restrict__ XG,    // [T][400]
    const float* __restrict__ Whh,   // [400][100]
    const float* __restrict__ wlin,  // [100]
    const float* __restrict__ blin,  // [1]
    float* __restrict__ out, int T)
{
    const int H = 100;
    __shared__ __align__(16) _Float16 hbuf[2][104];
    __shared__ __align__(16) float2 gbuf[100];   // {tanh(g), sigmoid(o)}
    __shared__ float hfin[100];
    const int j  = (int)threadIdx.x;
    const int wv = j >> 7;          // 0: gates i,f   1: gates g,o
    const int u  = j & 127;
    const bool active = u < H;
    const int uc = active ? u : (H - 1);   // clamp: all threads load valid rows

    const float4* p0 = (const float4*)(Whh + (size_t)(uc + (wv ? 200 : 0)) * H);
    const float4* p1 = (const float4*)(Whh + (size_t)(uc + (wv ? 300 : 100)) * H);

    // ---- per-thread weights: 2 rows x 52 packed f16, literal indices ----
    h2_t w0[52], w1[52];
#define LOADW(k) { \
    float4 a = p0[k]; float4 b = p1[k]; \
    w0[2*(k)]   = h2_t{(_Float16)a.x, (_Float16)a.y}; \
    w0[2*(k)+1] = h2_t{(_Float16)a.z, (_Float16)a.w}; \
    w1[2*(k)]   = h2_t{(_Float16)b.x, (_Float16)b.y}; \
    w1[2*(k)+1] = h2_t{(_Float16)b.z, (_Float16)b.w}; }
    LOADW(0)  LOADW(1)  LOADW(2)  LOADW(3)  LOADW(4)
    LOADW(5)  LOADW(6)  LOADW(7)  LOADW(8)  LOADW(9)
    LOADW(10) LOADW(11) LOADW(12) LOADW(13) LOADW(14)
    LOADW(15) LOADW(16) LOADW(17) LOADW(18) LOADW(19)
    LOADW(20) LOADW(21) LOADW(22) LOADW(23) LOADW(24)
#undef LOADW
    {
        h2_t z = h2_t{(_Float16)0.f, (_Float16)0.f};
        w0[50] = z; w0[51] = z; w1[50] = z; w1[51] = z;
    }

    // ---- pin every weight value: defeats rematerialization, forcing the
    //      allocator to keep all 104 dwords live in VGPRs (budget 512). ----
#define PINV(x) { unsigned _t = __builtin_bit_cast(unsigned, (x)); \
                  asm volatile("" : "+v"(_t)); \
                  (x) = __builtin_bit_cast(h2_t, _t); }
#define PINP(k) PINV(w0[k]) PINV(w1[k])
    PINP(0)  PINP(1)  PINP(2)  PINP(3)  PINP(4)  PINP(5)  PINP(6)
    PINP(7)  PINP(8)  PINP(9)  PINP(10) PINP(11) PINP(12) PINP(13)
    PINP(14) PINP(15) PINP(16) PINP(17) PINP(18) PINP(19) PINP(20)
    PINP(21) PINP(22) PINP(23) PINP(24) PINP(25) PINP(26) PINP(27)
    PINP(28) PINP(29) PINP(30) PINP(31) PINP(32) PINP(33) PINP(34)
    PINP(35) PINP(36) PINP(37) PINP(38) PINP(39) PINP(40) PINP(41)
    PINP(42) PINP(43) PINP(44) PINP(45) PINP(46) PINP(47) PINP(48)
    PINP(49) PINP(50) PINP(51)
#undef PINP
#undef PINV

    if (j < 104) { hbuf[0][j] = (_Float16)0.f; hbuf[1][j] = (_Float16)0.f; }

    // ---- depth-2 xg prefetch pipeline ----
    const int o0 = (wv ? 200 : 0) + u;
    const int o1 = (wv ? 300 : 100) + u;
    float x0 = 0.f, x1 = 0.f, p0v = 0.f, p1v = 0.f;
    if (active) {
        x0 = XG[o0]; x1 = XG[o1];
        if (T > 1) { p0v = XG[400 + o0]; p1v = XG[400 + o1]; }
    }

    float c = 0.f, hlast = 0.f;
    __syncthreads();

    int cur = 0;
    for (int t = 0; t < T; ++t) {
        float n0 = 0.f, n1 = 0.f;
        if (active && t + 2 < T) {
            const float* xr = XG + (size_t)(t + 2) * 400;
            n0 = xr[o0]; n1 = xr[o1];
        }

        float g0 = x0, g1 = x1;
        const _Float16* hc = hbuf[cur];
#define DOT4(r) { \
    float4 hv = *(const float4*)(hc + (r) * 8); \
    h2_t ha = __builtin_bit_cast(h2_t, hv.x); \
    h2_t hb = __builtin_bit_cast(h2_t, hv.y); \
    h2_t hcc = __builtin_bit_cast(h2_t, hv.z); \
    h2_t hd = __builtin_bit_cast(h2_t, hv.w); \
    g0 = __builtin_amdgcn_fdot2(w0[4*(r)+0], ha,  g0, false); \
    g1 = __builtin_amdgcn_fdot2(w1[4*(r)+0], ha,  g1, false); \
    g0 = __builtin_amdgcn_fdot2(w0[4*(r)+1], hb,  g0, false); \
    g1 = __builtin_amdgcn_fdot2(w1[4*(r)+1], hb,  g1, false); \
    g0 = __builtin_amdgcn_fdot2(w0[4*(r)+2], hcc, g0, false); \
    g1 = __builtin_amdgcn_fdot2(w1[4*(r)+2], hcc, g1, false); \
    g0 = __builtin_amdgcn_fdot2(w0[4*(r)+3], hd,  g0, false); \
    g1 = __builtin_amdgcn_fdot2(w1[4*(r)+3], hd,  g1, false); }
        DOT4(0)  DOT4(1)  DOT4(2)  DOT4(3)  DOT4(4)  DOT4(5)  DOT4(6)
        DOT4(7)  DOT4(8)  DOT4(9)  DOT4(10) DOT4(11) DOT4(12)
#undef DOT4

        if (active && wv) {               // group 1: finish g,o nonlinearity
            gbuf[u] = make_float2(tanh_fast(g0), sigmoid_fast(g1));
        }
        __syncthreads();
        if (active && !wv) {              // group 0: cell update
            float iv = sigmoid_fast(g0);
            float fv = sigmoid_fast(g1);
            float2 go = gbuf[u];
            c = fv * c + iv * go.x;
            float h = go.y * tanh_fast(c);
            hlast = h;
            hbuf[cur ^ 1][u] = (_Float16)h;
        }
        __syncthreads();
        cur ^= 1;
        x0 = p0v; x1 = p1v; p0v = n0; p1v = n1;
    }

    if (active && !wv) hfin[u] = hlast * wlin[u];
    __syncthreads();
    if (j == 0) {
        float acc = blin[0];
        for (int k = 0; k < H; ++k) acc += hfin[k];
        out[0] = acc;
    }
}

extern "C" void kernel_launch(void* const* d_in, const int* in_sizes, int n_in,
                              void* d_out, int out_size, void* d_ws, size_t ws_size,
                              hipStream_t stream) {
    const float* input = (const float*)d_in[0];  // [T][IN]
    const float* w_ih  = (const float*)d_in[1];  // [4H][IN]
    const float* w_hh  = (const float*)d_in[2];  // [4H][H]
    const float* b_ih  = (const float*)d_in[3];  // [4H]
    const float* b_hh  = (const float*)d_in[4];  // [4H]
    const float* w_lin = (const float*)d_in[5];  // [H]
    const float* b_lin = (const float*)d_in[6];  // [1]
    float* out = (float*)d_out;

    const int FH = in_sizes[3];            // 400
    const int IN = in_sizes[1] / FH;       // 3000
    const int T  = in_sizes[0] / IN;       // 8192

    float* xg = (float*)d_ws;              // [T][FH] = 13.1 MB

    dim3 grid((T + GBM - 1) / GBM, (FH + GBN - 1) / GBN);
    gates_gemm<<<grid, 256, 0, stream>>>(input, w_ih, b_ih, b_hh, xg, T, IN, FH);
    lstm_scan4<<<1, 256, 0, stream>>>(xg, w_hh, w_lin, b_lin, out, T);
}

// Round 6
// 7191.635 us; speedup vs baseline: 1.0466x; 1.0466x over previous
//
#include <hip/hip_runtime.h>
#include <hip/hip_bf16.h>

// LSTM: T=8192, IN=3000, H=100 (4H=400), torch gate order i,f,g,o.
// Phase 1: xg[T][400] = input_seq @ w_ih^T + (b_ih + b_hh)   (fp32 tiled GEMM)
// Phase 2: single-workgroup scan, 256 threads / 4 waves.
//   Group 0 (tid<128): unit u, gate rows u (i), u+100 (f)
//   Group 1 (tid>=128): unit u, gate rows u+200 (g), u+300 (o)
// ROUND-6 FIX: R1-R5 kept w_hh in SCRATCH, not registers — the h2_t w[52]
// arrays were allocas SROA never promoted (R5 proof: VGPR=104 unchanged and
// pinning array elements only added scratch round-trips). Now the 104 weight
// dwords are 104 NAMED SCALARS (mem2reg promotes unconditionally), each
// pinned once via "+v" asm so the backend cannot remat-from-memory per use.

#define GBM 128
#define GBN 128
#define GBK 16

typedef _Float16 h2_t __attribute__((ext_vector_type(2)));

__global__ __launch_bounds__(256) void gates_gemm(
    const float* __restrict__ A,    // [T][IN]
    const float* __restrict__ W,    // [FH][IN]
    const float* __restrict__ bih,  // [FH]
    const float* __restrict__ bhh,  // [FH]
    float* __restrict__ XG,         // [T][FH]
    int T, int IN, int FH)
{
    __shared__ __align__(16) float As[GBK][GBM];
    __shared__ __align__(16) float Bs[GBK][GBN];
    const int bm = blockIdx.x * GBM;
    const int bn = blockIdx.y * GBN;
    const int tid = (int)threadIdx.x;
    const int tx = tid & 15, ty = tid >> 4;

    float acc[8][8];
    #pragma unroll
    for (int i = 0; i < 8; ++i)
        #pragma unroll
        for (int j = 0; j < 8; ++j) acc[i][j] = 0.f;

    for (int k0 = 0; k0 < IN; k0 += GBK) {
        __syncthreads();
        #pragma unroll
        for (int q = 0; q < 2; ++q) {
            int idx = tid + q * 256;
            int row = idx >> 2;
            int kq  = (idx & 3) << 2;
            int gk  = k0 + kq;
            float4 av = make_float4(0.f, 0.f, 0.f, 0.f);
            float4 bv = make_float4(0.f, 0.f, 0.f, 0.f);
            if (gk < IN) {
                av = *(const float4*)&A[(size_t)(bm + row) * IN + gk];
                if (bn + row < FH)
                    bv = *(const float4*)&W[(size_t)(bn + row) * IN + gk];
            }
            As[kq + 0][row] = av.x; As[kq + 1][row] = av.y;
            As[kq + 2][row] = av.z; As[kq + 3][row] = av.w;
            Bs[kq + 0][row] = bv.x; Bs[kq + 1][row] = bv.y;
            Bs[kq + 2][row] = bv.z; Bs[kq + 3][row] = bv.w;
        }
        __syncthreads();
        #pragma unroll
        for (int kk = 0; kk < GBK; ++kk) {
            float4 a0 = *(const float4*)&As[kk][ty * 4];
            float4 a1 = *(const float4*)&As[kk][64 + ty * 4];
            float4 b0 = *(const float4*)&Bs[kk][tx * 4];
            float4 b1 = *(const float4*)&Bs[kk][64 + tx * 4];
            float am[8] = {a0.x, a0.y, a0.z, a0.w, a1.x, a1.y, a1.z, a1.w};
            float bn_[8] = {b0.x, b0.y, b0.z, b0.w, b1.x, b1.y, b1.z, b1.w};
            #pragma unroll
            for (int i = 0; i < 8; ++i)
                #pragma unroll
                for (int j = 0; j < 8; ++j)
                    acc[i][j] = fmaf(am[i], bn_[j], acc[i][j]);
        }
    }

    #pragma unroll
    for (int i = 0; i < 8; ++i) {
        int r = bm + ((i < 4) ? (ty * 4 + i) : (64 + ty * 4 + (i - 4)));
        #pragma unroll
        for (int j = 0; j < 8; ++j) {
            int cidx = bn + ((j < 4) ? (tx * 4 + j) : (64 + tx * 4 + (j - 4)));
            if (cidx < FH)
                XG[(size_t)r * FH + cidx] = acc[i][j] + bih[cidx] + bhh[cidx];
        }
    }
}

__device__ __forceinline__ float sigmoid_fast(float x) {
    return 1.f / (1.f + __expf(-x));
}
__device__ __forceinline__ float tanh_fast(float x) {
    // tanh(x) = 1 - 2/(exp(2x)+1); exp saturation gives correct +-1 limits.
    return 1.f - 2.f / (__expf(2.f * x) + 1.f);
}

__global__ __launch_bounds__(256, 1) void lstm_scan5(
    const float* __restrict__ XG,    // [T][400]
    const float* __restrict__ Whh,   // [400][100]
    const float* __restrict__ wlin,  // [100]
    const float* __restrict__ blin,  // [1]
    float* __restrict__ out, int T)
{
    const int H = 100;
    __shared__ __align__(16) _Float16 hbuf[2][104];
    __shared__ __align__(16) float2 gbuf[100];   // {tanh(g), sigmoid(o)}
    __shared__ float hfin[100];
    const int j  = (int)threadIdx.x;
    const int wv = j >> 7;          // 0: gates i,f   1: gates g,o
    const int u  = j & 127;
    const bool active = u < H;
    const int uc = active ? u : (H - 1);   // clamp: all threads load valid rows

    const float4* p0 = (const float4*)(Whh + (size_t)(uc + (wv ? 200 : 0)) * H);
    const float4* p1 = (const float4*)(Whh + (size_t)(uc + (wv ? 300 : 100)) * H);

    // ---- 104 NAMED weight scalars (no arrays -> guaranteed mem2reg) ----
#define DECL2(k) h2_t W0_##k, W1_##k;
    DECL2(0)  DECL2(1)  DECL2(2)  DECL2(3)  DECL2(4)  DECL2(5)  DECL2(6)
    DECL2(7)  DECL2(8)  DECL2(9)  DECL2(10) DECL2(11) DECL2(12) DECL2(13)
    DECL2(14) DECL2(15) DECL2(16) DECL2(17) DECL2(18) DECL2(19) DECL2(20)
    DECL2(21) DECL2(22) DECL2(23) DECL2(24) DECL2(25) DECL2(26) DECL2(27)
    DECL2(28) DECL2(29) DECL2(30) DECL2(31) DECL2(32) DECL2(33) DECL2(34)
    DECL2(35) DECL2(36) DECL2(37) DECL2(38) DECL2(39) DECL2(40) DECL2(41)
    DECL2(42) DECL2(43) DECL2(44) DECL2(45) DECL2(46) DECL2(47) DECL2(48)
    DECL2(49) DECL2(50) DECL2(51)
#undef DECL2

#define LOADW(k, a, b) { \
    float4 xa = p0[k]; float4 xb = p1[k]; \
    W0_##a = h2_t{(_Float16)xa.x, (_Float16)xa.y}; \
    W0_##b = h2_t{(_Float16)xa.z, (_Float16)xa.w}; \
    W1_##a = h2_t{(_Float16)xb.x, (_Float16)xb.y}; \
    W1_##b = h2_t{(_Float16)xb.z, (_Float16)xb.w}; }
    LOADW(0,0,1)   LOADW(1,2,3)   LOADW(2,4,5)   LOADW(3,6,7)   LOADW(4,8,9)
    LOADW(5,10,11) LOADW(6,12,13) LOADW(7,14,15) LOADW(8,16,17) LOADW(9,18,19)
    LOADW(10,20,21) LOADW(11,22,23) LOADW(12,24,25) LOADW(13,26,27)
    LOADW(14,28,29) LOADW(15,30,31) LOADW(16,32,33) LOADW(17,34,35)
    LOADW(18,36,37) LOADW(19,38,39) LOADW(20,40,41) LOADW(21,42,43)
    LOADW(22,44,45) LOADW(23,46,47) LOADW(24,48,49)
#undef LOADW
    {
        h2_t z = h2_t{(_Float16)0.f, (_Float16)0.f};
        W0_50 = z; W0_51 = z; W1_50 = z; W1_51 = z;
    }

    // ---- pin each SSA value once: blocks remat-from-memory per use ----
#define PIN1(x) { float _pf = __builtin_bit_cast(float, x); \
                  asm("" : "+v"(_pf)); \
                  x = __builtin_bit_cast(h2_t, _pf); }
#define PIN(k) PIN1(W0_##k) PIN1(W1_##k)
    PIN(0)  PIN(1)  PIN(2)  PIN(3)  PIN(4)  PIN(5)  PIN(6)
    PIN(7)  PIN(8)  PIN(9)  PIN(10) PIN(11) PIN(12) PIN(13)
    PIN(14) PIN(15) PIN(16) PIN(17) PIN(18) PIN(19) PIN(20)
    PIN(21) PIN(22) PIN(23) PIN(24) PIN(25) PIN(26) PIN(27)
    PIN(28) PIN(29) PIN(30) PIN(31) PIN(32) PIN(33) PIN(34)
    PIN(35) PIN(36) PIN(37) PIN(38) PIN(39) PIN(40) PIN(41)
    PIN(42) PIN(43) PIN(44) PIN(45) PIN(46) PIN(47) PIN(48)
    PIN(49) PIN(50) PIN(51)
#undef PIN
#undef PIN1

    if (j < 104) { hbuf[0][j] = (_Float16)0.f; hbuf[1][j] = (_Float16)0.f; }

    // ---- depth-2 xg prefetch pipeline ----
    const int o0 = (wv ? 200 : 0) + u;
    const int o1 = (wv ? 300 : 100) + u;
    float x0 = 0.f, x1 = 0.f, p0v = 0.f, p1v = 0.f;
    if (active) {
        x0 = XG[o0]; x1 = XG[o1];
        if (T > 1) { p0v = XG[400 + o0]; p1v = XG[400 + o1]; }
    }

    float c = 0.f, hlast = 0.f;
    __syncthreads();

    int cur = 0;
    for (int t = 0; t < T; ++t) {
        float n0 = 0.f, n1 = 0.f;
        if (active && t + 2 < T) {
            const float* xr = XG + (size_t)(t + 2) * 400;
            n0 = xr[o0]; n1 = xr[o1];
        }

        float g0 = x0, g1 = x1;
        const _Float16* hc = hbuf[cur];
#define DOTR(r, a, b, cc, d) { \
    float4 hv = *(const float4*)(hc + (r) * 8); \
    h2_t ha = __builtin_bit_cast(h2_t, hv.x); \
    h2_t hb = __builtin_bit_cast(h2_t, hv.y); \
    h2_t hx = __builtin_bit_cast(h2_t, hv.z); \
    h2_t hd = __builtin_bit_cast(h2_t, hv.w); \
    g0 = __builtin_amdgcn_fdot2(W0_##a,  ha, g0, false); \
    g1 = __builtin_amdgcn_fdot2(W1_##a,  ha, g1, false); \
    g0 = __builtin_amdgcn_fdot2(W0_##b,  hb, g0, false); \
    g1 = __builtin_amdgcn_fdot2(W1_##b,  hb, g1, false); \
    g0 = __builtin_amdgcn_fdot2(W0_##cc, hx, g0, false); \
    g1 = __builtin_amdgcn_fdot2(W1_##cc, hx, g1, false); \
    g0 = __builtin_amdgcn_fdot2(W0_##d,  hd, g0, false); \
    g1 = __builtin_amdgcn_fdot2(W1_##d,  hd, g1, false); }
        DOTR(0,0,1,2,3)     DOTR(1,4,5,6,7)     DOTR(2,8,9,10,11)
        DOTR(3,12,13,14,15) DOTR(4,16,17,18,19) DOTR(5,20,21,22,23)
        DOTR(6,24,25,26,27) DOTR(7,28,29,30,31) DOTR(8,32,33,34,35)
        DOTR(9,36,37,38,39) DOTR(10,40,41,42,43) DOTR(11,44,45,46,47)
        DOTR(12,48,49,50,51)
#undef DOTR

        float iv = 0.f, fv = 0.f;
        if (wv) {                 // group 1: finish g,o nonlinearity pre-barrier
            if (active) gbuf[u] = make_float2(tanh_fast(g0), sigmoid_fast(g1));
        } else {                  // group 0: start i,f sigmoids pre-barrier
            iv = sigmoid_fast(g0);
            fv = sigmoid_fast(g1);
        }
        __syncthreads();
        if (active && !wv) {      // group 0: short post-barrier tail
            float2 go = gbuf[u];
            c = fv * c + iv * go.x;
            float h = go.y * tanh_fast(c);
            hlast = h;
            hbuf[cur ^ 1][u] = (_Float16)h;
        }
        __syncthreads();
        cur ^= 1;
        x0 = p0v; x1 = p1v; p0v = n0; p1v = n1;
    }

    if (active && !wv) hfin[u] = hlast * wlin[u];
    __syncthreads();
    if (j == 0) {
        float acc = blin[0];
        for (int k = 0; k < H; ++k) acc += hfin[k];
        out[0] = acc;
    }
}

extern "C" void kernel_launch(void* const* d_in, const int* in_sizes, int n_in,
                              void* d_out, int out_size, void* d_ws, size_t ws_size,
                              hipStream_t stream) {
    const float* input = (const float*)d_in[0];  // [T][IN]
    const float* w_ih  = (const float*)d_in[1];  // [4H][IN]
    const float* w_hh  = (const float*)d_in[2];  // [4H][H]
    const float* b_ih  = (const float*)d_in[3];  // [4H]
    const float* b_hh  = (const float*)d_in[4];  // [4H]
    const float* w_lin = (const float*)d_in[5];  // [H]
    const float* b_lin = (const float*)d_in[6];  // [1]
    float* out = (float*)d_out;

    const int FH = in_sizes[3];            // 400
    const int IN = in_sizes[1] / FH;       // 3000
    const int T  = in_sizes[0] / IN;       // 8192

    float* xg = (float*)d_ws;              // [T][FH] = 13.1 MB

    dim3 grid((T + GBM - 1) / GBM, (FH + GBN - 1) / GBN);
    gates_gemm<<<grid, 256, 0, stream>>>(input, w_ih, b_ih, b_hh, xg, T, IN, FH);
    lstm_scan5<<<1, 256, 0, stream>>>(xg, w_hh, w_lin, b_lin, out, T);
}

// Round 8
// 5227.351 us; speedup vs baseline: 1.4398x; 1.3758x over previous
//
#include <hip/hip_runtime.h>
#include <hip/hip_bf16.h>

// LSTM: T=8192, IN=3000, H=100 (4H=400), torch gate order i,f,g,o.
// Phase 1: xg[T][400] = input @ w_ih^T + (b_ih+b_hh), written PERMUTED:
//          column 4u+g  <-  original column u+100g  (unit-major gate packing)
// Phase 2: single-workgroup scan, 256 threads / 4 waves, MFMA-based:
//   w_hh rows permuted to R=4u+g; K padded 100->128; M=400 -> 25 tiles of 16,
//   split 7/6/6/6 across waves. A-fragments pinned in PHYSICAL AGPRs a0..a111
//   (written once via v_accvgpr_write; allocator can't spill/remat them).
//   B = h (f16, LDS, double-buffered) broadcast to 16 cols; D layout
//   (col=lane&15, row=4*(lane>>4)+reg) gives lane 16q+col all 4 gates of
//   unit 4*(tb+col)+q in its 4 acc regs -> in-lane elementwise, 1 barrier/step.
// ROUND-8 FIX vs R7 (absmax 8.8e-3): MFMA results have NO HW interlock vs
// VALU reads; the compiler interleaved the accumulator-select cndmasks
// between the volatile MFMA blocks, reading accs inside the hazard window
// (deterministic partial-sum corruption). Now every acc read is gated on a
// volatile guard asm (s_nop 7 x2 -> colg) emitted AFTER the last MFMA, so
// no read can be scheduled closer than ~16+ cycles after the final MFMA.

#define GBM 128
#define GBN 128
#define GBK 16

typedef _Float16 h2_t  __attribute__((ext_vector_type(2)));
typedef _Float16 f16x8 __attribute__((ext_vector_type(8)));
typedef float    f32x4 __attribute__((ext_vector_type(4)));

__global__ __launch_bounds__(256) void gates_gemm(
    const float* __restrict__ A,    // [T][IN]
    const float* __restrict__ W,    // [FH][IN]
    const float* __restrict__ bih,  // [FH]
    const float* __restrict__ bhh,  // [FH]
    float* __restrict__ XG,         // [T][FH]  (permuted columns)
    int T, int IN, int FH)
{
    __shared__ __align__(16) float As[GBK][GBM];
    __shared__ __align__(16) float Bs[GBK][GBN];
    const int bm = blockIdx.x * GBM;
    const int bn = blockIdx.y * GBN;
    const int tid = (int)threadIdx.x;
    const int tx = tid & 15, ty = tid >> 4;
    const int H = FH >> 2;   // 100

    float acc[8][8];
    #pragma unroll
    for (int i = 0; i < 8; ++i)
        #pragma unroll
        for (int j = 0; j < 8; ++j) acc[i][j] = 0.f;

    for (int k0 = 0; k0 < IN; k0 += GBK) {
        __syncthreads();
        #pragma unroll
        for (int q = 0; q < 2; ++q) {
            int idx = tid + q * 256;
            int row = idx >> 2;
            int kq  = (idx & 3) << 2;
            int gk  = k0 + kq;
            float4 av = make_float4(0.f, 0.f, 0.f, 0.f);
            float4 bv = make_float4(0.f, 0.f, 0.f, 0.f);
            if (gk < IN) {
                av = *(const float4*)&A[(size_t)(bm + row) * IN + gk];
                if (bn + row < FH)
                    bv = *(const float4*)&W[(size_t)(bn + row) * IN + gk];
            }
            As[kq + 0][row] = av.x; As[kq + 1][row] = av.y;
            As[kq + 2][row] = av.z; As[kq + 3][row] = av.w;
            Bs[kq + 0][row] = bv.x; Bs[kq + 1][row] = bv.y;
            Bs[kq + 2][row] = bv.z; Bs[kq + 3][row] = bv.w;
        }
        __syncthreads();
        #pragma unroll
        for (int kk = 0; kk < GBK; ++kk) {
            float4 a0 = *(const float4*)&As[kk][ty * 4];
            float4 a1 = *(const float4*)&As[kk][64 + ty * 4];
            float4 b0 = *(const float4*)&Bs[kk][tx * 4];
            float4 b1 = *(const float4*)&Bs[kk][64 + tx * 4];
            float am[8] = {a0.x, a0.y, a0.z, a0.w, a1.x, a1.y, a1.z, a1.w};
            float bn_[8] = {b0.x, b0.y, b0.z, b0.w, b1.x, b1.y, b1.z, b1.w};
            #pragma unroll
            for (int i = 0; i < 8; ++i)
                #pragma unroll
                for (int j = 0; j < 8; ++j)
                    acc[i][j] = fmaf(am[i], bn_[j], acc[i][j]);
        }
    }

    #pragma unroll
    for (int i = 0; i < 8; ++i) {
        int r = bm + ((i < 4) ? (ty * 4 + i) : (64 + ty * 4 + (i - 4)));
        #pragma unroll
        for (int j = 0; j < 8; ++j) {
            int cidx = bn + ((j < 4) ? (tx * 4 + j) : (64 + tx * 4 + (j - 4)));
            if (cidx < FH) {
                int pc = 4 * (cidx % H) + cidx / H;   // unit-major permutation
                XG[(size_t)r * FH + pc] = acc[i][j] + bih[cidx] + bhh[cidx];
            }
        }
    }
}

__device__ __forceinline__ float sigmoid_fast(float x) {
    return 1.f / (1.f + __expf(-x));
}
__device__ __forceinline__ float tanh_fast(float x) {
    return 1.f - 2.f / (__expf(2.f * x) + 1.f);
}

// pack W[k], W[k+1] (f32) into one dword of two f16 (zero past K=100)
__device__ __forceinline__ float pack_pair(const float* rp, int k) {
    float a = 0.f, b = 0.f;
    if (k < 100) { a = rp[k]; b = rp[k + 1]; }
    h2_t p = {(_Float16)a, (_Float16)b};
    return __builtin_bit_cast(float, p);
}

#define ACLOB \
    "a0","a1","a2","a3","a4","a5","a6","a7","a8","a9","a10","a11","a12","a13",\
    "a14","a15","a16","a17","a18","a19","a20","a21","a22","a23","a24","a25",\
    "a26","a27","a28","a29","a30","a31","a32","a33","a34","a35","a36","a37",\
    "a38","a39","a40","a41","a42","a43","a44","a45","a46","a47","a48","a49",\
    "a50","a51","a52","a53","a54","a55","a56","a57","a58","a59","a60","a61",\
    "a62","a63","a64","a65","a66","a67","a68","a69","a70","a71","a72","a73",\
    "a74","a75","a76","a77","a78","a79","a80","a81","a82","a83","a84","a85",\
    "a86","a87","a88","a89","a90","a91","a92","a93","a94","a95","a96","a97",\
    "a98","a99","a100","a101","a102","a103","a104","a105","a106","a107",\
    "a108","a109","a110","a111"

#define WRW(N, V) \
    asm volatile("v_accvgpr_write_b32 a" #N ", %0" :: "v"(V) : "a" #N)

#define LF(m, ks, N0, N1, N2, N3) { \
    const int kb_ = 32 * (ks) + 8 * q; \
    WRW(N0, pack_pair(rowp[m], kb_ + 0)); \
    WRW(N1, pack_pair(rowp[m], kb_ + 2)); \
    WRW(N2, pack_pair(rowp[m], kb_ + 4)); \
    WRW(N3, pack_pair(rowp[m], kb_ + 6)); }

#define MFMA_OP(ACC, AR, B, PRE) \
    asm volatile(PRE "v_mfma_f32_16x16x32_f16 %0, " AR ", %1, %0" \
                 : "+v"(ACC) : "v"(B) : ACLOB)

#define TILE4(ACC, R0, R1, R2, R3) \
    MFMA_OP(ACC, R0, b0, "s_nop 1\n\t"); \
    MFMA_OP(ACC, R1, b1, ""); \
    MFMA_OP(ACC, R2, b2, ""); \
    MFMA_OP(ACC, R3, b3, "")

__global__ __launch_bounds__(256, 1) void lstm_scan_mfma(
    const float* __restrict__ XGp,   // [T][400] permuted (4u+g)
    const float* __restrict__ Whh,   // [400][100] original layout
    const float* __restrict__ wlin,  // [100]
    const float* __restrict__ blin,  // [1]
    float* __restrict__ out, int T)
{
    __shared__ __align__(16) _Float16 hbuf[2][128];  // h (f16), K-padded
    __shared__ float hfin[100];
    const int tid = (int)threadIdx.x;
    const int w   = tid >> 6;        // wave 0..3
    const int l   = tid & 63;
    const int q   = l >> 4;          // row-group / k-block 0..3
    const int col = l & 15;          // MFMA column = tile selector
    const int NT  = (w == 0) ? 7 : 6;
    const int tb  = (w == 0) ? 0 : 7 + 6 * (w - 1);   // 0,7,13,19

    // per-lane weight row pointers for this wave's 7 tile slots
    const float* rowp[7];
    #pragma unroll
    for (int m = 0; m < 7; ++m) {
        int mg = tb + m; if (mg > 24) mg = 24;        // clamp pad tile
        int R  = 16 * mg + col;                       // permuted row 4u+g
        rowp[m] = Whh + (size_t)((R >> 2) + 100 * (R & 3)) * 100;
    }

    // ---- load A-fragments into PHYSICAL AGPRs a0..a111 (once) ----
    LF(0,0,  0,  1,  2,  3)  LF(0,1,  4,  5,  6,  7)
    LF(0,2,  8,  9, 10, 11)  LF(0,3, 12, 13, 14, 15)
    LF(1,0, 16, 17, 18, 19)  LF(1,1, 20, 21, 22, 23)
    LF(1,2, 24, 25, 26, 27)  LF(1,3, 28, 29, 30, 31)
    LF(2,0, 32, 33, 34, 35)  LF(2,1, 36, 37, 38, 39)
    LF(2,2, 40, 41, 42, 43)  LF(2,3, 44, 45, 46, 47)
    LF(3,0, 48, 49, 50, 51)  LF(3,1, 52, 53, 54, 55)
    LF(3,2, 56, 57, 58, 59)  LF(3,3, 60, 61, 62, 63)
    LF(4,0, 64, 65, 66, 67)  LF(4,1, 68, 69, 70, 71)
    LF(4,2, 72, 73, 74, 75)  LF(4,3, 76, 77, 78, 79)
    LF(5,0, 80, 81, 82, 83)  LF(5,1, 84, 85, 86, 87)
    LF(5,2, 88, 89, 90, 91)  LF(5,3, 92, 93, 94, 95)
    LF(6,0, 96, 97, 98, 99)  LF(6,1,100,101,102,103)
    LF(6,2,104,105,106,107)  LF(6,3,108,109,110,111)

    if (tid < 128) {
        hbuf[0][tid] = (_Float16)0.f;
        hbuf[1][tid] = (_Float16)0.f;
    }

    // elementwise lane mapping: lane 16q+col handles unit 4*(tb+col)+q
    const bool act = (col < NT);
    const int  u   = act ? (4 * (tb + col) + q) : 0;

    // depth-2 xg prefetch (per-lane float4 = 4 gates of unit u)
    f32x4 x_cur = *(const f32x4*)(XGp + 4 * u);
    f32x4 x_nxt = *(const f32x4*)(XGp + (size_t)(T > 1 ? 1 : 0) * 400 + 4 * u);

    float c = 0.f, hlast = 0.f;
    __syncthreads();

    int cur = 0;
    for (int t = 0; t < T; ++t) {
        int tp = (t + 2 < T) ? (t + 2) : (T - 1);
        f32x4 x_new = *(const f32x4*)(XGp + (size_t)tp * 400 + 4 * u);

        // B fragments: h broadcast to all 16 columns; k = 32*ks + 8*q + j
        const _Float16* hb = hbuf[cur];
        f16x8 b0 = *(const f16x8*)(hb +       8 * q);
        f16x8 b1 = *(const f16x8*)(hb +  32 + 8 * q);
        f16x8 b2 = *(const f16x8*)(hb +  64 + 8 * q);
        f16x8 b3 = *(const f16x8*)(hb +  96 + 8 * q);

        f32x4 acc0 = {0.f, 0.f, 0.f, 0.f};
        f32x4 acc1 = acc0, acc2 = acc0, acc3 = acc0;
        f32x4 acc4 = acc0, acc5 = acc0, acc6 = acc0;

        TILE4(acc0, "a[0:3]",    "a[4:7]",     "a[8:11]",    "a[12:15]");
        TILE4(acc1, "a[16:19]",  "a[20:23]",   "a[24:27]",   "a[28:31]");
        TILE4(acc2, "a[32:35]",  "a[36:39]",   "a[40:43]",   "a[44:47]");
        TILE4(acc3, "a[48:51]",  "a[52:55]",   "a[56:59]",   "a[60:63]");
        TILE4(acc4, "a[64:67]",  "a[68:71]",   "a[72:75]",   "a[76:79]");
        TILE4(acc5, "a[80:83]",  "a[84:87]",   "a[88:91]",   "a[92:95]");
        TILE4(acc6, "a[96:99]",  "a[100:103]", "a[104:107]", "a[108:111]");

        // ---- hazard guard: no acc may be read before this point ----
        // (volatile, after the last MFMA block; 16 cycles of s_nop, then
        //  colg <- col. Every select below uses colg, so the compiler
        //  cannot hoist any accumulator read into the MFMA hazard window.)
        int colg;
        asm volatile("s_nop 7\n\ts_nop 7\n\tv_or_b32 %0, 0, %1"
                     : "=v"(colg) : "v"(col));

        f32x4 g = (colg == 1) ? acc1 : acc0;
        g = (colg == 2) ? acc2 : g;
        g = (colg == 3) ? acc3 : g;
        g = (colg == 4) ? acc4 : g;
        g = (colg == 5) ? acc5 : g;
        g = (colg == 6) ? acc6 : g;

        float iv = sigmoid_fast(g[0] + x_cur[0]);
        float fv = sigmoid_fast(g[1] + x_cur[1]);
        float gv = tanh_fast   (g[2] + x_cur[2]);
        float ov = sigmoid_fast(g[3] + x_cur[3]);
        c = fv * c + iv * gv;
        float h = ov * tanh_fast(c);
        if (act) {
            hlast = h;
            hbuf[cur ^ 1][u] = (_Float16)h;
        }
        __syncthreads();
        cur ^= 1;
        x_cur = x_nxt; x_nxt = x_new;
    }

    if (act) hfin[u] = hlast * wlin[u];
    __syncthreads();
    if (tid == 0) {
        float s = blin[0];
        for (int k = 0; k < 100; ++k) s += hfin[k];
        out[0] = s;
    }
}

extern "C" void kernel_launch(void* const* d_in, const int* in_sizes, int n_in,
                              void* d_out, int out_size, void* d_ws, size_t ws_size,
                              hipStream_t stream) {
    const float* input = (const float*)d_in[0];  // [T][IN]
    const float* w_ih  = (const float*)d_in[1];  // [4H][IN]
    const float* w_hh  = (const float*)d_in[2];  // [4H][H]
    const float* b_ih  = (const float*)d_in[3];  // [4H]
    const float* b_hh  = (const float*)d_in[4];  // [4H]
    const float* w_lin = (const float*)d_in[5];  // [H]
    const float* b_lin = (const float*)d_in[6];  // [1]
    float* out = (float*)d_out;

    const int FH = in_sizes[3];            // 400
    const int IN = in_sizes[1] / FH;       // 3000
    const int T  = in_sizes[0] / IN;       // 8192

    float* xg = (float*)d_ws;              // [T][FH] = 13.1 MB (permuted)

    dim3 grid((T + GBM - 1) / GBM, (FH + GBN - 1) / GBN);
    gates_gemm<<<grid, 256, 0, stream>>>(input, w_ih, b_ih, b_hh, xg, T, IN, FH);
    lstm_scan_mfma<<<1, 256, 0, stream>>>(xg, w_hh, w_lin, b_lin, out, T);
}